// Round 4
// baseline (137.196 us; speedup 1.0000x reference)
//
#include <hip/hip_runtime.h>

// WaveletLoss: 3-level Haar DWT + soft-threshold + weighted mean-abs-diff.
// B=64, C=1, H=W=512.
// R11 = R10 RETRY (previous round died in the broker: "container failed
// twice", no compile/test/counter output -- infra, not kernel).
// Probe: cache-bypass reads. R7 (nt), R8 (launch-bounds), R9 (persistent
// pipelined grid) ALL neutral -> no read-issue-pattern theory survives.
// Theory: the harness poison fill (exactly 256 MiB = MALL size, 6.6 TB/s
// at the TCC boundary) leaves dirty lines in MALL; during main either
// (a) MALL->HBM drain steals ~half the bus, or (b) main's read-allocations
// evict dirty poison lines forcing ~134 MB writeback inside main's window.
// Both give 134R + ~134W = 6.7 TB/s combined = observed "3.4 TB/s read wall".
// (b) is kernel-fixable: no-allocate reads never evict. Probe: inline-asm
// global_load_dwordx4 sc0 sc1 nt (system-scope, no-allocate). Explicit
// s_waitcnt vmcnt(0) + sched_barrier(0) before use (asm loads are invisible
// to compiler vmcnt tracking). Tiling = R7's simple 8192-tile version.
// If neutral -> theory (a), compulsory poison traffic -> ROOFLINE.

#define IMG_W 512
#define N_BATCH 64

#define THR1 (50.0f / 255.0f)
#define THR2 (25.0f / 255.0f)
#define THR3 (12.5f / 255.0f)

#define NBLK 2048   // 2048 blocks * 4 waves = 8192 tiles of 8x256

typedef float v4f __attribute__((ext_vector_type(4)));

__device__ __forceinline__ float softthr(float x, float thr) {
    float m = fmaxf(fabsf(x) - thr, 0.0f);
    return copysignf(m, x);
}

__device__ __forceinline__ float detail_term(float p, float t, float thr) {
    return fabsf(softthr(p, thr) - softthr(t, thr));
}

__device__ __forceinline__ void haar_quad(float a, float b, float c, float d,
                                          float& cA, float& cH, float& cV, float& cD) {
    cA = 0.5f * (a + b + c + d);
    cH = 0.5f * (a + b - c - d);
    cV = 0.5f * (a - b + c - d);
    cD = 0.5f * (a - b - c + d);
}

// Bypass loads: sc0 sc1 = system-scope (no L0/L2 allocate), nt = no MALL
// temporal allocate. Compiler does NOT track these in vmcnt -- caller must
// s_waitcnt vmcnt(0) + sched_barrier(0) before consuming.
#define LD4B0(dst, base)                                                      \
    asm volatile("global_load_dwordx4 %0, %1, off sc0 sc1 nt"                 \
                 : "=v"(dst) : "v"(base) : "memory")
#define LD4B1(dst, base)                                                      \
    asm volatile("global_load_dwordx4 %0, %1, off offset:2048 sc0 sc1 nt"     \
                 : "=v"(dst) : "v"(base) : "memory")

__global__ __launch_bounds__(256, 4)
void wavelet_main(const float* __restrict__ pred,
                  const float* __restrict__ target,
                  float* __restrict__ ws) {
    constexpr float W1 = 1.0f / (1.0f * 3.0f * (float)(N_BATCH * 256 * 256));
    constexpr float W2 = 1.0f / (2.0f * 3.0f * (float)(N_BATCH * 128 * 128));
    constexpr float W3 = 1.0f / (3.0f * 3.0f * (float)(N_BATCH * 64 * 64));

    const int T  = blockIdx.x * 4 + (threadIdx.x >> 6);   // tile id 0..8191
    const int li = threadIdx.x & 63;

    const int img   = T >> 7;
    const int rem   = T & 127;
    const int half  = rem & 1;
    const int strip = rem >> 1;               // 8-row strip 0..63

    const size_t off = (size_t)img * (512 * 512)
                     + (size_t)strip * 8 * IMG_W
                     + half * 256 + 4 * li;

    // base pointers every 2 rows; offset:2048 covers the odd row
    const float* pb0 = pred + off;
    const float* pb2 = pb0 + 2 * IMG_W;
    const float* pb4 = pb0 + 4 * IMG_W;
    const float* pb6 = pb0 + 6 * IMG_W;
    const float* tb0 = target + off;
    const float* tb2 = tb0 + 2 * IMG_W;
    const float* tb4 = tb0 + 4 * IMG_W;
    const float* tb6 = tb0 + 6 * IMG_W;

    v4f P0, P1, P2, P3, P4, P5, P6, P7;
    v4f Q0, Q1, Q2, Q3, Q4, Q5, Q6, Q7;

    LD4B0(P0, pb0);  LD4B1(P1, pb0);
    LD4B0(P2, pb2);  LD4B1(P3, pb2);
    LD4B0(P4, pb4);  LD4B1(P5, pb4);
    LD4B0(P6, pb6);  LD4B1(P7, pb6);
    LD4B0(Q0, tb0);  LD4B1(Q1, tb0);
    LD4B0(Q2, tb2);  LD4B1(Q3, tb2);
    LD4B0(Q4, tb4);  LD4B1(Q5, tb4);
    LD4B0(Q6, tb6);  LD4B1(Q7, tb6);

    asm volatile("s_waitcnt vmcnt(0)" ::: "memory");
    __builtin_amdgcn_sched_barrier(0);

    float s1 = 0.0f, s2 = 0.0f;
    float cA1p[4][2], cA1t[4][2];

    // ---- level 1: row-pairs (2rp, 2rp+1), two quads per pair (in-lane) ----
    {
        float cA, cH, cV, cD, cAt, cHt, cVt, cDt;

        #define L1_PAIR(a, b, qa, qb, rp)                                              \
        {                                                                              \
            haar_quad((a).x, (a).y, (b).x, (b).y, cA, cH, cV, cD);                     \
            haar_quad((qa).x, (qa).y, (qb).x, (qb).y, cAt, cHt, cVt, cDt);             \
            s1 += detail_term(cH, cHt, THR1) + detail_term(cV, cVt, THR1)              \
                + detail_term(cD, cDt, THR1);                                          \
            cA1p[rp][0] = cA; cA1t[rp][0] = cAt;                                       \
            haar_quad((a).z, (a).w, (b).z, (b).w, cA, cH, cV, cD);                     \
            haar_quad((qa).z, (qa).w, (qb).z, (qb).w, cAt, cHt, cVt, cDt);             \
            s1 += detail_term(cH, cHt, THR1) + detail_term(cV, cVt, THR1)              \
                + detail_term(cD, cDt, THR1);                                          \
            cA1p[rp][1] = cA; cA1t[rp][1] = cAt;                                       \
        }

        L1_PAIR(P0, P1, Q0, Q1, 0)
        L1_PAIR(P2, P3, Q2, Q3, 1)
        L1_PAIR(P4, P5, Q4, Q5, 2)
        L1_PAIR(P6, P7, Q6, Q7, 3)
        #undef L1_PAIR
    }

    // ---- level 2: two quads fully in-lane ----
    float cA2p[2], cA2t[2];
    {
        float cH, cV, cD, cHt, cVt, cDt;
        haar_quad(cA1p[0][0], cA1p[0][1], cA1p[1][0], cA1p[1][1], cA2p[0], cH, cV, cD);
        haar_quad(cA1t[0][0], cA1t[0][1], cA1t[1][0], cA1t[1][1], cA2t[0], cHt, cVt, cDt);
        s2 += detail_term(cH, cHt, THR2) + detail_term(cV, cVt, THR2) + detail_term(cD, cDt, THR2);
        haar_quad(cA1p[2][0], cA1p[2][1], cA1p[3][0], cA1p[3][1], cA2p[1], cH, cV, cD);
        haar_quad(cA1t[2][0], cA1t[2][1], cA1t[3][0], cA1t[3][1], cA2t[1], cHt, cVt, cDt);
        s2 += detail_term(cH, cHt, THR2) + detail_term(cV, cVt, THR2) + detail_term(cD, cDt, THR2);
    }

    // ---- level 3: horizontal neighbor via shfl_xor(1), vertical in-lane ----
    float s3;
    {
        const float bP = __shfl_xor(cA2p[0], 1);
        const float dP = __shfl_xor(cA2p[1], 1);
        const float bT = __shfl_xor(cA2t[0], 1);
        const float dT = __shfl_xor(cA2t[1], 1);
        float cA, cH, cV, cD, cAt, cHt, cVt, cDt;
        haar_quad(cA2p[0], bP, cA2p[1], dP, cA, cH, cV, cD);
        haar_quad(cA2t[0], bT, cA2t[1], dT, cAt, cHt, cVt, cDt);
        s3 = detail_term(cH, cHt, THR3) + detail_term(cV, cVt, THR3) + detail_term(cD, cDt, THR3);
    }
    const float w3 = (li & 1) ? 0.0f : W3;

    float acc = W1 * s1 + W2 * s2 + w3 * s3;

    // wave reduction (64 lanes)
    #pragma unroll
    for (int off = 32; off > 0; off >>= 1)
        acc += __shfl_down(acc, off, 64);

    __shared__ float wave_sums[4];
    const int lane_b = threadIdx.x & 63;
    const int wave_b = threadIdx.x >> 6;
    if (lane_b == 0) wave_sums[wave_b] = acc;
    __syncthreads();
    if (threadIdx.x == 0)
        ws[blockIdx.x] = wave_sums[0] + wave_sums[1] + wave_sums[2] + wave_sums[3];
}

__global__ __launch_bounds__(256)
void wavelet_reduce(const float* __restrict__ ws, float* __restrict__ out) {
    const int tidx = threadIdx.x;
    float v = 0.0f;
    #pragma unroll
    for (int k = 0; k < NBLK / 256; ++k)
        v += ws[tidx + k * 256];

    #pragma unroll
    for (int off = 32; off > 0; off >>= 1)
        v += __shfl_down(v, off, 64);

    __shared__ float wave_sums[4];
    const int lane = tidx & 63;
    const int wave = tidx >> 6;
    if (lane == 0) wave_sums[wave] = v;
    __syncthreads();
    if (tidx == 0)
        out[0] = wave_sums[0] + wave_sums[1] + wave_sums[2] + wave_sums[3];
}

extern "C" void kernel_launch(void* const* d_in, const int* in_sizes, int n_in,
                              void* d_out, int out_size, void* d_ws, size_t ws_size,
                              hipStream_t stream) {
    const float* pred   = (const float*)d_in[0];
    const float* target = (const float*)d_in[1];
    float* out = (float*)d_out;
    float* ws  = (float*)d_ws;   // NBLK floats = 8 KB

    wavelet_main<<<NBLK, 256, 0, stream>>>(pred, target, ws);
    wavelet_reduce<<<1, 256, 0, stream>>>(ws, out);
}